// Round 1
// baseline (187.522 us; speedup 1.0000x reference)
//
#include <hip/hip_runtime.h>
#include <stdint.h>

// QuantizedPatternMatcher — R16: drop MFMA formulation entirely.
//
// Evidence (R15 rocprof): top-5 dispatches are ALL 256MiB ws-poison fills at
// 42.32-43.08us => both our kernels < 42.32us, yet dur=84.8 => one ~42.4us
// fill is inside the metric (fixed floor). Addressable time ~= 42.4us =
// prep(~5) + match(~37). match is 4.9x its mfma_scale-fp4 floor (7.6us) and
// R6-R15 eliminated every scheduling theory => cost is intrinsic to the
// mfma_scale/VALU-expand formulation.
//
// R16: bitplane popcount. 3-bit bin codes packed as 3 bitplanes x 16 u32
// chunks per 512 dims (48 dwords / 192 B per row or pattern). Per (row,pat):
// mismatch = sum_16 popc((x0^p0)|(x1^p1)|(x2^p2)) -> 6 VALU per 32 dims ->
// 96 VALU/pair -> 10.2us VALU floor chip-wide (vs MFMA floor 7.6 but no
// mystery pipe). lane=row holds 48-reg row planes; 64-pattern LDS stage read
// via broadcast ds_read_b128, double-buffered (prA/prB, static indices only).
// Argmax = min-key (mis<<10)|pat via atomicMin (exact ref tie-break: max
// matches then lowest pattern index). Integer-exact end to end.
#define NROW 8192
#define NPAT 1024

typedef unsigned int u32;

__device__ __forceinline__ u32 bin7(float v, float e0, float e1, float e2,
                                    float e3, float e4, float e5, float e6) {
  return (u32)((v > e0) + (v > e1) + (v > e2) + (v > e3) + (v > e4) +
               (v > e5) + (v > e6));
}

__device__ __forceinline__ void acc3(u32 b, int k, u32& p0, u32& p1, u32& p2) {
  p0 |= (b & 1u) << k;
  p1 |= ((b >> 1) & 1u) << k;
  p2 |= ((b >> 2) & 1u) << k;
}

// ---------------------------------------------------------------------------
// prep: quantize + pack bitplanes.
//   xplanes [8192][16][3] u32   (row-major: 48 dwords = 192 B per row)
//   pplanes [1024][16][3] u32
//   keys    [8192] u32 = 0xFFFFFFFF  (atomicMin targets; ws is poisoned
//                                     every iteration so we must re-init)
// Thread i handles one (row, chunk32): reads 128 B contiguous, writes 12 B.
// ---------------------------------------------------------------------------
__global__ __launch_bounds__(256) void prep_pc(
    const float* __restrict__ x, const float* __restrict__ patterns,
    const float* __restrict__ edges, u32* __restrict__ xplanes,
    u32* __restrict__ pplanes, u32* __restrict__ keys) {
  const int bid = blockIdx.x, tid = threadIdx.x;
  if (bid >= 576) {  // 32 blocks: init keys
    const int r = (bid - 576) * 256 + tid;
    keys[r] = 0xFFFFFFFFu;
    return;
  }
  const float e0 = edges[0], e1 = edges[1], e2 = edges[2], e3 = edges[3],
              e4 = edges[4], e5 = edges[5], e6 = edges[6];
  const float4* s4;
  u32* dst;
  if (bid < 512) {  // x: 8192 rows * 16 chunks = 131072 threads
    const int i = bid * 256 + tid;  // i = row*16 + chunk
    s4 = reinterpret_cast<const float4*>(x + (size_t)i * 32);
    dst = xplanes + (size_t)i * 3;
  } else {  // patterns: 1024 * 16 = 16384 threads
    const int j = (bid - 512) * 256 + tid;
    s4 = reinterpret_cast<const float4*>(patterns + (size_t)j * 32);
    dst = pplanes + (size_t)j * 3;
  }
  u32 p0 = 0, p1 = 0, p2 = 0;
#pragma unroll
  for (int q = 0; q < 8; ++q) {
    const float4 a = s4[q];
    acc3(bin7(a.x, e0, e1, e2, e3, e4, e5, e6), q * 4 + 0, p0, p1, p2);
    acc3(bin7(a.y, e0, e1, e2, e3, e4, e5, e6), q * 4 + 1, p0, p1, p2);
    acc3(bin7(a.z, e0, e1, e2, e3, e4, e5, e6), q * 4 + 2, p0, p1, p2);
    acc3(bin7(a.w, e0, e1, e2, e3, e4, e5, e6), q * 4 + 3, p0, p1, p2);
  }
  dst[0] = p0;
  dst[1] = p1;
  dst[2] = p2;
}

// Load one pattern's 48 plane dwords from LDS via 12 broadcast b128 reads.
__device__ __forceinline__ void loadpat48(u32 (&d)[48],
                                          const u32* __restrict__ s) {
#pragma unroll
  for (int j = 0; j < 12; ++j) {
    const uint4 v = *reinterpret_cast<const uint4*>(s + j * 4);
    d[j * 4 + 0] = v.x;
    d[j * 4 + 1] = v.y;
    d[j * 4 + 2] = v.z;
    d[j * 4 + 3] = v.w;
  }
}

// 16 chunks x (3 xor + 2 or + 1 popc-acc) = ~96 VALU, then min-key update.
__device__ __forceinline__ u32 stepf(const u32 (&rp)[48], const u32 (&pr)[48],
                                     u32 patid, u32 best) {
  u32 mis = 0;
#pragma unroll
  for (int c = 0; c < 16; ++c) {
    const u32 d = (rp[c * 3 + 0] ^ pr[c * 3 + 0]) |
                  (rp[c * 3 + 1] ^ pr[c * 3 + 1]) |
                  (rp[c * 3 + 2] ^ pr[c * 3 + 2]);
    mis = (u32)__popc(d) + mis;
  }
  const u32 key = (mis << 10) | patid;
  return key < best ? key : best;
}

// ---------------------------------------------------------------------------
// match: grid 256 = 16 row-blocks (512 rows, lane=row) x 16 pattern-chunks
// (64 patterns). 512 thr = 8 waves = 2 waves/SIMD. Row planes: 48 VGPR.
// Pattern chunk: 12.5 KB LDS, read broadcast (uniform addr, conflict-free),
// double-buffered prA/prB with static indexing (no scratch). VALU-bound:
// ~2x100x2x2 = 800 cyc/SIMD per 2 patterns vs LDS ~288 -> hidden.
// ---------------------------------------------------------------------------
__global__ __launch_bounds__(512, 2) void match_pc(
    const u32* __restrict__ xplanes, const u32* __restrict__ pplanes,
    u32* __restrict__ keys) {
  __shared__ __align__(16) u32 lpat[65 * 48];  // +1 pattern: benign over-read
  const int tid = threadIdx.x;
  const int rb = blockIdx.x >> 4;
  const int ph = blockIdx.x & 15;
  const int row = rb * 512 + tid;

  {  // stage 64 patterns' planes (3072 dwords), coalesced
    const u32* __restrict__ src = pplanes + (size_t)ph * (64 * 48);
    for (int k = tid; k < 64 * 48; k += 512) lpat[k] = src[k];
  }

  u32 rp[48];
  {
    const uint4* __restrict__ rs =
        reinterpret_cast<const uint4*>(xplanes + (size_t)row * 48);
#pragma unroll
    for (int j = 0; j < 12; ++j) {
      const uint4 v = rs[j];
      rp[j * 4 + 0] = v.x;
      rp[j * 4 + 1] = v.y;
      rp[j * 4 + 2] = v.z;
      rp[j * 4 + 3] = v.w;
    }
  }
  __syncthreads();

  u32 prA[48], prB[48];
  loadpat48(prA, lpat);
  u32 best = 0xFFFFFFFFu;
  const u32 pb = (u32)(ph << 6);
  for (int p = 0; p < 64; p += 2) {
    loadpat48(prB, &lpat[(p + 1) * 48]);
    best = stepf(rp, prA, pb + (u32)p, best);
    loadpat48(prA, &lpat[(p + 2) * 48]);  // p=62 reads pad slot 64: unused
    best = stepf(rp, prB, pb + (u32)p + 1u, best);
  }
  atomicMin(&keys[row], best);
}

__global__ __launch_bounds__(256) void fixup_pc(const u32* __restrict__ keys,
                                                float* __restrict__ out) {
  const int r = blockIdx.x * 256 + threadIdx.x;
  const u32 k = keys[r];
  out[r] = (float)(k & 1023u);
  out[NROW + r] = (float)(512u - (k >> 10)) * (1.0f / 512.0f);
}

extern "C" void kernel_launch(void* const* d_in, const int* in_sizes, int n_in,
                              void* d_out, int out_size, void* d_ws,
                              size_t ws_size, hipStream_t stream) {
  const float* x = (const float*)d_in[0];         // [8192, 512] f32
  const float* patterns = (const float*)d_in[1];  // [1024, 512] f32
  const float* edges = (const float*)d_in[2];     // [7] f32
  float* out = (float*)d_out;                     // 16384 f32

  u32* xplanes = (u32*)d_ws;                       // 1.57 MB
  u32* pplanes = xplanes + (size_t)NROW * 48;      // 196 KB
  u32* keys = pplanes + (size_t)NPAT * 48;         // 32 KB

  prep_pc<<<608, 256, 0, stream>>>(x, patterns, edges, xplanes, pplanes, keys);
  match_pc<<<256, 512, 0, stream>>>(xplanes, pplanes, keys);
  fixup_pc<<<32, 256, 0, stream>>>(keys, out);
}